// Round 6
// baseline (4409.579 us; speedup 1.0000x reference)
//
#include <hip/hip_runtime.h>
#include <math.h>
#include <stdint.h>

#define STEPS 127
#define NBLK 32
#define NTHR 512
#define CAP 160

typedef unsigned int uint;

struct GDParams {
  const int* node_types; const int* esrc; const int* edst; const float* he;
  const float* enc_W; const float* enc_b; const float* msg_W; const float* msg_b;
  const float* Wih; const float* Whh; const float* bih; const float* bhh;
  unsigned* bar;          // [0]=counter [1]=generation (setup barrier)
  unsigned* slots;        // [NBLK] per-block round slots (fast barrier)
  uint* bufb0; uint* bufb1;   // hv published as bf16 pairs [128][64]
  float* g;               // 16256 gumbel values
  unsigned short* Wp;     // bf16 packed weights [mt(6)][kc(16)][j(384)][8k]
  float* W2T;             // [2][16][384] f32
  float* bm2;             // [2][384]
  float* HeSum;           // [127][128][16]
  float* degs;            // [127][128]
  unsigned char* alive;   // [127][128]
  unsigned char* hasE;    // [127]
  int* victims; int* row_ptr; int* in_count; int* cursor; int* col_src; int* col_eid;
  int* misc;              // [0]=survivor, [1+v]=death step (127 = never)
  float* out;             // 257 floats: hv[surv](128) | victim_order(128) | logps(1)
};

__device__ __forceinline__ void tfround(unsigned &x0, unsigned &x1, int r) {
  x0 += x1; x1 = (x1 << r) | (x1 >> (32 - r)); x1 ^= x0;
}
__device__ void threefry2x32(unsigned k0, unsigned k1, unsigned c0, unsigned c1,
                             unsigned &o0, unsigned &o1) {
  unsigned ks2 = k0 ^ k1 ^ 0x1BD11BDAu;
  unsigned x0 = c0 + k0, x1 = c1 + k1;
  tfround(x0,x1,13); tfround(x0,x1,15); tfround(x0,x1,26); tfround(x0,x1,6);
  x0 += k1; x1 += ks2 + 1u;
  tfround(x0,x1,17); tfround(x0,x1,29); tfround(x0,x1,16); tfround(x0,x1,24);
  x0 += ks2; x1 += k0 + 2u;
  tfround(x0,x1,13); tfround(x0,x1,15); tfround(x0,x1,26); tfround(x0,x1,6);
  x0 += k0; x1 += k1 + 3u;
  tfround(x0,x1,17); tfround(x0,x1,29); tfround(x0,x1,16); tfround(x0,x1,24);
  x0 += k1; x1 += ks2 + 4u;
  tfround(x0,x1,13); tfround(x0,x1,15); tfround(x0,x1,26); tfround(x0,x1,6);
  x0 += ks2; x1 += k0 + 5u;
  o0 = x0; o1 = x1;
}
__device__ __forceinline__ float gumbel_from_bits(unsigned b) {
  unsigned fb = (b >> 9) | 0x3F800000u;
  float f = __uint_as_float(fb) - 1.0f;
  const float tiny = 1.17549435e-38f;
  float u = fmaxf(tiny, f * (1.0f - tiny) + tiny);
  return -logf(-logf(u));
}

__device__ __forceinline__ unsigned short f2bf(float f) {
  unsigned u = __float_as_uint(f);
  unsigned r = (u + 0x7FFFu + ((u >> 16) & 1u)) >> 16;
  return (unsigned short)r;
}
__device__ __forceinline__ float bflo(uint w) { return __uint_as_float(w << 16); }
__device__ __forceinline__ float bfhi(uint w) { return __uint_as_float(w & 0xFFFF0000u); }

#if __has_builtin(__builtin_amdgcn_fdot2_f32_bf16)
typedef __bf16 bf2 __attribute__((ext_vector_type(2)));
__device__ __forceinline__ float dot2bf(uint a, uint b, float c) {
  return __builtin_amdgcn_fdot2_f32_bf16(__builtin_bit_cast(bf2, a),
                                         __builtin_bit_cast(bf2, b), c, false);
}
#else
__device__ __forceinline__ float dot2bf(uint a, uint b, float c) {
  return fmaf(bflo(a), bflo(b), fmaf(bfhi(a), bfhi(b), c));
}
#endif

// sc1 (agent-coherent) data path
__device__ __forceinline__ uint ld_devu(const uint* a) {
  return __hip_atomic_load(const_cast<uint*>(a), __ATOMIC_RELAXED, __HIP_MEMORY_SCOPE_AGENT);
}
__device__ __forceinline__ void st_devu(uint* a, uint v) {
  __hip_atomic_store(a, v, __ATOMIC_RELAXED, __HIP_MEMORY_SCOPE_AGENT);
}

// heavyweight setup barrier (acq/rel; publishes plain-written setup data)
__device__ __forceinline__ void gsync(unsigned* bar, unsigned &mygen) {
  __syncthreads();
  mygen++;
  if (threadIdx.x == 0) {
    unsigned prev = __hip_atomic_fetch_add(&bar[0], 1u, __ATOMIC_ACQ_REL, __HIP_MEMORY_SCOPE_AGENT);
    if (prev == (unsigned)(gridDim.x - 1u)) {
      __hip_atomic_store(&bar[0], 0u, __ATOMIC_RELAXED, __HIP_MEMORY_SCOPE_AGENT);
      __hip_atomic_store(&bar[1], mygen, __ATOMIC_RELEASE, __HIP_MEMORY_SCOPE_AGENT);
    } else {
      long guard = 0;
      while (__hip_atomic_load(&bar[1], __ATOMIC_ACQUIRE, __HIP_MEMORY_SCOPE_AGENT) != mygen) {
        if (++guard > (1L << 30)) break;
      }
    }
  }
  __syncthreads();
}

// split fast barrier with sleep backoff
__device__ __forceinline__ void bpost(unsigned* slots, unsigned r) {
  __syncthreads();   // drains vmcnt -> hv sc1-stores visible before slot post
  if (threadIdx.x == 0)
    __hip_atomic_store(&slots[blockIdx.x], r, __ATOMIC_RELAXED, __HIP_MEMORY_SCOPE_AGENT);
}
__device__ __forceinline__ void bwait(unsigned* slots, unsigned r) {
  if (threadIdx.x < 64) {
    int lane = threadIdx.x;
    long guard = 0;
    for (;;) {
      unsigned v = (lane < NBLK)
        ? __hip_atomic_load(&slots[lane], __ATOMIC_RELAXED, __HIP_MEMORY_SCOPE_AGENT)
        : 0xFFFFFFFFu;
      if (__all(v >= r)) break;
      __builtin_amdgcn_s_sleep(1);     // backoff: cut MALL poll contention
      if (++guard > (1L << 20)) break; // safety valve
    }
  }
  __builtin_amdgcn_fence(__ATOMIC_ACQUIRE, "workgroup");  // ordering only
  __syncthreads();
}

__global__ __launch_bounds__(NTHR, 1) void gd_main(GDParams p) {
  __shared__ float pgq[4][4][384];            // Wq partials [kquarter][node][j]
  __shared__ float pgr[2][4][384];            // Wr partials [khalf][node][j]
  __shared__ float pgh[2][4][384];            // Whh partials
  __shared__ float pgHe[4][384];              // He + bih + deg*bm2
  __shared__ alignas(16) uint S_u[4][64];     // S bf16-pairs
  __shared__ alignas(16) uint hv_u[4][64];    // own hv bf16-pairs
  __shared__ float hv_f[4][128];              // own hv fp32 master
  __shared__ int colL[4][CAP];
  __shared__ int cntL[4]; __shared__ int rpL[4];
  __shared__ float degL[4]; __shared__ int aliveL[4];
  __shared__ int victimL; __shared__ int hasEL;
  __shared__ int pfs[128];

  const int tid = threadIdx.x;
  const int gtid = blockIdx.x * NTHR + tid;
  const int GSZ = NBLK * NTHR;
  unsigned mygen = 0;

  // ---------- Stage A ----------
  if (blockIdx.x == 0) {
    // jax_threefry_partitionable (default since 0.4.36): ctr=(0,i), bits=o0^o1
    for (int i = tid; i < 16256; i += NTHR) {
      unsigned o0, o1; threefry2x32(0u, 42u, 0u, (unsigned)i, o0, o1);
      p.g[i] = gumbel_from_bits(o0 ^ o1);
    }
    __syncthreads();
    if (tid < 64) {
      int lane = tid;
      bool a0 = true, a1 = true;
      float lsum = 0.f;
      p.misc[1 + lane] = 127; p.misc[1 + 64 + lane] = 127;
      for (int s = 0; s < STEPS; ++s) {
        p.alive[s * 128 + lane] = a0 ? 1 : 0;
        p.alive[s * 128 + 64 + lane] = a1 ? 1 : 0;
        float c = logf(1.0f / (float)(128 - s));
        float g0 = a0 ? (c + p.g[s * 128 + lane]) : -INFINITY;
        float g1 = a1 ? (c + p.g[s * 128 + 64 + lane]) : -INFINITY;
        float bv; int bi;
        if (g0 >= g1) { bv = g0; bi = lane; } else { bv = g1; bi = lane + 64; }
        for (int off = 32; off > 0; off >>= 1) {
          float ov = __shfl_down(bv, off);
          int   oi = __shfl_down(bi, off);
          if (ov > bv || (ov == bv && oi < bi)) { bv = ov; bi = oi; }
        }
        int victim = __shfl(bi, 0);
        if (victim == lane) { a0 = false; p.misc[1 + lane] = s; }
        if (victim == lane + 64) { a1 = false; p.misc[1 + 64 + lane] = s; }
        lsum += c;
        if (lane == 0) {
          p.victims[s] = victim;
          p.out[128 + 127 - s] = (float)victim;
        }
      }
      unsigned long long m0 = __ballot(a0), m1 = __ballot(a1);
      int surv = m0 ? (__ffsll(m0) - 1) : (64 + __ffsll(m1) - 1);
      if (lane == 0) { p.misc[0] = surv; p.out[128] = (float)surv; p.out[256] = lsum; }
    }
  } else {
    const int g63 = (blockIdx.x - 1) * NTHR + tid;
    const int GSZ63 = (NBLK - 1) * NTHR;
    for (int i = g63; i < 128; i += GSZ63) { p.in_count[i] = 0; p.cursor[i] = 0; }
    // hv0 published as bf16 pairs
    for (int i = g63; i < 8192; i += GSZ63) {
      int v = i >> 6, up = i & 63;
      int ty = p.node_types[v];
      float h0 = p.enc_W[(2 * up) * 32 + ty] + p.enc_b[2 * up];
      float h1 = p.enc_W[(2 * up + 1) * 32 + ty] + p.enc_b[2 * up + 1];
      p.bufb0[i] = (uint)f2bf(h0) | ((uint)f2bf(h1) << 16);
    }
    // folded Wq = Wih@Wa (mat 0), Wr = Wih@Wb (mat 1) -> bf16 packed layout
    for (int o = g63; o < 196608; o += GSZ63) {
      int mat = o / 98304; int r = o % 98304; int t = r / 49152; int rr = r % 49152;
      int k = rr / 384, j = rr % 384;
      const float* wih = p.Wih + (size_t)(t * 384 + j) * 128;
      const float* mw  = p.msg_W + (size_t)t * 128 * 272 + (mat * 128 + k);
      float acc = 0.f;
      for (int m = 0; m < 128; ++m) acc += wih[m] * mw[(size_t)m * 272];
      int mt = mat * 2 + t;
      p.Wp[(size_t)((mt * 16 + (k >> 3)) * 384 + j) * 8 + (k & 7)] = f2bf(acc);
    }
    // Whh -> bf16 packed (mt = 4+t)
    for (int o = g63; o < 98304; o += GSZ63) {
      int t = o / 49152; int rr = o % 49152; int k = rr / 384, j = rr % 384;
      float acc = p.Whh[(size_t)(t * 384 + j) * 128 + k];
      int mt = 4 + t;
      p.Wp[(size_t)((mt * 16 + (k >> 3)) * 384 + j) * 8 + (k & 7)] = f2bf(acc);
    }
    // W2T = (Wih@We)^T f32 [t][16][384]
    for (int o = g63; o < 12288; o += GSZ63) {
      int t = o / 6144; int rr = o % 6144; int k = rr / 384, j = rr % 384;
      const float* wih = p.Wih + (size_t)(t * 384 + j) * 128;
      const float* mw  = p.msg_W + (size_t)t * 128 * 272 + (256 + k);
      float acc = 0.f;
      for (int m = 0; m < 128; ++m) acc += wih[m] * mw[(size_t)m * 272];
      p.W2T[(size_t)(t * 16 + k) * 384 + j] = acc;
    }
    // bm2 = Wih @ msg_b
    for (int o = g63; o < 768; o += GSZ63) {
      int t = o / 384, j = o % 384;
      const float* wih = p.Wih + (size_t)(t * 384 + j) * 128;
      const float* mb = p.msg_b + t * 128;
      float acc = 0.f;
      for (int m = 0; m < 128; ++m) acc += wih[m] * mb[m];
      p.bm2[o] = acc;
    }
  }
  gsync(p.bar, mygen);

  // ---------- Stage B: in-degree histogram ----------
  if (blockIdx.x != 0) {
    for (int e = (blockIdx.x - 1) * NTHR + tid; e < 2048; e += (NBLK - 1) * NTHR)
      atomicAdd(&p.in_count[p.edst[e]], 1);
  }
  gsync(p.bar, mygen);

  // ---------- Stage C: prefix sum (block 0) ----------
  if (blockIdx.x == 0) {
    if (tid < 128) pfs[tid] = p.in_count[tid];
    __syncthreads();
    for (int off = 1; off < 128; off <<= 1) {
      int add = 0;
      if (tid < 128 && tid >= off) add = pfs[tid - off];
      __syncthreads();
      if (tid < 128) pfs[tid] += add;
      __syncthreads();
    }
    if (tid == 0) p.row_ptr[0] = 0;
    if (tid < 128) p.row_ptr[tid + 1] = pfs[tid];
  }
  gsync(p.bar, mygen);

  // ---------- Stage D: CSR scatter ----------
  for (int e = gtid; e < 2048; e += GSZ) {
    int dd = p.edst[e];
    int pos = atomicAdd(&p.cursor[dd], 1);
    int q = p.row_ptr[dd] + pos;
    p.col_src[q] = p.esrc[e];
    p.col_eid[q] = e;
  }
  gsync(p.bar, mygen);

  // ---------- Stage E: per-step deg / HeSum ----------
  for (int i = gtid; i < 16256; i += GSZ) {
    int s = i >> 7, v = i & 127;
    int rp0 = p.row_ptr[v], rp1 = p.row_ptr[v + 1];
    const unsigned char* al = p.alive + s * 128;
    float deg = 0.f; float hacc[16];
    #pragma unroll
    for (int k = 0; k < 16; ++k) hacc[k] = 0.f;
    for (int q = rp0; q < rp1; ++q) {
      int u = p.col_src[q];
      if (al[u]) {
        deg += 1.f;
        const float* hr = p.he + (size_t)p.col_eid[q] * 16;
        #pragma unroll
        for (int k = 0; k < 16; ++k) hacc[k] += hr[k];
      }
    }
    p.degs[i] = deg;
    float* ho = p.HeSum + (size_t)i * 16;
    #pragma unroll
    for (int k = 0; k < 16; ++k) ho[k] = hacc[k];
  }
  gsync(p.bar, mygen);

  // ---------- Stage F: has_edges + per-block CSR preload ----------
  for (int s = gtid; s < STEPS; s += GSZ) {
    float acc = 0.f;
    for (int v = 0; v < 128; ++v)
      acc += p.alive[s * 128 + v] ? p.degs[s * 128 + v] : 0.f;
    p.hasE[s] = (acc > 0.f) ? 1 : 0;
  }
  for (int vv = 0; vv < 4; ++vv) {
    int v = blockIdx.x * 4 + vv;
    int rp0 = p.row_ptr[v], rp1 = p.row_ptr[v + 1];
    if (tid == 0) { cntL[vv] = rp1 - rp0; rpL[vv] = rp0; }
    int n = rp1 - rp0; if (n > CAP) n = CAP;
    for (int q = tid; q < n; q += NTHR) colL[vv][q] = p.col_src[rp0 + q];
  }
  gsync(p.bar, mygen);   // publishes all setup data

  // ---------- Main loop ----------
  const uint* curb = p.bufb0; uint* nxtb = p.bufb1;
  const int wave = tid >> 6, lane6 = tid & 63;
  const int myv4 = blockIdx.x * 4;
  const uint4* Wp4 = (const uint4*)p.Wp;

  const int surv = p.misc[0];
  int bexitS;
  {
    int m0 = p.misc[1 + myv4], m1 = p.misc[2 + myv4];
    int m2 = p.misc[3 + myv4], m3 = p.misc[4 + myv4];
    bexitS = max(max(m0, m1), max(m2, m3));   // 127 if block holds survivor
  }

  // init hv mirrors
  {
    int n = tid >> 7, d = tid & 127;
    int ty = p.node_types[myv4 + n];
    float h0 = p.enc_W[d * 32 + ty] + p.enc_b[d];
    hv_f[n][d] = h0;
    float ph = __shfl_xor(h0, 1);
    if ((tid & 1) == 0) hv_u[n][d >> 1] = (uint)f2bf(h0) | ((uint)f2bf(ph) << 16);
  }
  __syncthreads();

  unsigned r = 0;
  for (int s = 0; s < STEPS; ++s) {
    for (int t = 0; t < 2; ++t) {
      r++;
      bpost(p.slots, r);

      // ---- pre-wait shadow: local GEMVs (Wr, Whh) + step scalars + He/bias ----
      if (tid == 0) { victimL = p.victims[s]; hasEL = p.hasE[s]; }
      if (tid < 4) {
        degL[tid] = p.degs[s * 128 + myv4 + tid];
        aliveL[tid] = p.alive[s * 128 + myv4 + tid];
      }
      {
        const int mm = wave & 1, H = (wave >> 1) & 1, P = wave >> 2;
        const uint4* WM = Wp4 + (size_t)((mm ? 4 : 2) + t) * 6144;
        const uint4* A0 = (const uint4*)&hv_u[P * 2][0];
        const uint4* A1 = (const uint4*)&hv_u[P * 2 + 1][0];
        float acc[6][2] = {};
        #pragma unroll
        for (int kc = 0; kc < 8; ++kc) {
          int kcg = H * 8 + kc;
          uint4 a0 = A0[kcg], a1 = A1[kcg];
          #pragma unroll
          for (int jj = 0; jj < 6; ++jj) {
            uint4 wv = WM[(size_t)kcg * 384 + lane6 + 64 * jj];
            acc[jj][0] = dot2bf(a0.x, wv.x, acc[jj][0]);
            acc[jj][0] = dot2bf(a0.y, wv.y, acc[jj][0]);
            acc[jj][0] = dot2bf(a0.z, wv.z, acc[jj][0]);
            acc[jj][0] = dot2bf(a0.w, wv.w, acc[jj][0]);
            acc[jj][1] = dot2bf(a1.x, wv.x, acc[jj][1]);
            acc[jj][1] = dot2bf(a1.y, wv.y, acc[jj][1]);
            acc[jj][1] = dot2bf(a1.z, wv.z, acc[jj][1]);
            acc[jj][1] = dot2bf(a1.w, wv.w, acc[jj][1]);
          }
        }
        float (*dst)[4][384] = mm ? pgh : pgr;
        #pragma unroll
        for (int jj = 0; jj < 6; ++jj) {
          dst[H][P * 2][lane6 + 64 * jj] = acc[jj][0];
          dst[H][P * 2 + 1][lane6 + 64 * jj] = acc[jj][1];
        }
      }
      #pragma unroll
      for (int ii = 0; ii < 3; ++ii) {
        int idx = tid + 512 * ii;
        int n2 = idx / 384, j = idx - n2 * 384;
        int v = myv4 + n2;
        float dg = p.degs[s * 128 + v];
        float a = p.bih[t * 384 + j] + dg * p.bm2[t * 384 + j];
        const float* hs = p.HeSum + ((size_t)s * 128 + v) * 16;
        #pragma unroll
        for (int k2 = 0; k2 < 16; ++k2)
          a += hs[k2] * p.W2T[(size_t)(t * 16 + k2) * 384 + j];
        pgHe[n2][j] = a;
      }

      bwait(p.slots, r);

      // ---- gather S: (node, dim-pair, edge-half) over all 512 threads ----
      {
        int n = tid >> 7, u = (tid >> 1) & 63, e = tid & 1;
        int cnt = cntL[n];
        int cmin = cnt < CAP ? cnt : CAP;
        float aL = 0.f, aH = 0.f;
        int q = e;
        for (; q + 14 < cmin; q += 16) {
          int c0 = colL[n][q],      c1 = colL[n][q + 2],  c2 = colL[n][q + 4],  c3 = colL[n][q + 6];
          int c4 = colL[n][q + 8],  c5 = colL[n][q + 10], c6 = colL[n][q + 12], c7 = colL[n][q + 14];
          uint w0 = ld_devu(&curb[(size_t)c0 * 64 + u]);
          uint w1 = ld_devu(&curb[(size_t)c1 * 64 + u]);
          uint w2 = ld_devu(&curb[(size_t)c2 * 64 + u]);
          uint w3 = ld_devu(&curb[(size_t)c3 * 64 + u]);
          uint w4 = ld_devu(&curb[(size_t)c4 * 64 + u]);
          uint w5 = ld_devu(&curb[(size_t)c5 * 64 + u]);
          uint w6 = ld_devu(&curb[(size_t)c6 * 64 + u]);
          uint w7 = ld_devu(&curb[(size_t)c7 * 64 + u]);
          aL += ((bflo(w0) + bflo(w1)) + (bflo(w2) + bflo(w3)))
              + ((bflo(w4) + bflo(w5)) + (bflo(w6) + bflo(w7)));
          aH += ((bfhi(w0) + bfhi(w1)) + (bfhi(w2) + bfhi(w3)))
              + ((bfhi(w4) + bfhi(w5)) + (bfhi(w6) + bfhi(w7)));
        }
        for (; q < cnt; q += 2) {
          int c = (q < CAP) ? colL[n][q] : p.col_src[rpL[n] + q];
          uint w = ld_devu(&curb[(size_t)c * 64 + u]);
          aL += bflo(w); aH += bfhi(w);
        }
        aL += __shfl_xor(aL, 1);
        aH += __shfl_xor(aH, 1);
        if (e == 0) S_u[n][u] = (uint)f2bf(aL) | ((uint)f2bf(aH) << 16);
      }
      __syncthreads();

      // ---- Wq . S on all 8 waves (quarter-K x node-pair) ----
      {
        const int qq = wave & 3, P = (wave >> 2) & 1;
        const uint4* WQ = Wp4 + (size_t)t * 6144;
        const uint4* A0 = (const uint4*)&S_u[P * 2][0];
        const uint4* A1 = (const uint4*)&S_u[P * 2 + 1][0];
        float acc[6][2] = {};
        #pragma unroll
        for (int kc = 0; kc < 4; ++kc) {
          int kcg = qq * 4 + kc;
          uint4 a0 = A0[kcg], a1 = A1[kcg];
          #pragma unroll
          for (int jj = 0; jj < 6; ++jj) {
            uint4 wv = WQ[(size_t)kcg * 384 + lane6 + 64 * jj];
            acc[jj][0] = dot2bf(a0.x, wv.x, acc[jj][0]);
            acc[jj][0] = dot2bf(a0.y, wv.y, acc[jj][0]);
            acc[jj][0] = dot2bf(a0.z, wv.z, acc[jj][0]);
            acc[jj][0] = dot2bf(a0.w, wv.w, acc[jj][0]);
            acc[jj][1] = dot2bf(a1.x, wv.x, acc[jj][1]);
            acc[jj][1] = dot2bf(a1.y, wv.y, acc[jj][1]);
            acc[jj][1] = dot2bf(a1.z, wv.z, acc[jj][1]);
            acc[jj][1] = dot2bf(a1.w, wv.w, acc[jj][1]);
          }
        }
        #pragma unroll
        for (int jj = 0; jj < 6; ++jj) {
          pgq[qq][P * 2][lane6 + 64 * jj] = acc[jj][0];
          pgq[qq][P * 2 + 1][lane6 + 64 * jj] = acc[jj][1];
        }
      }
      __syncthreads();

      // ---- gates + hv update + publish ----
      {
        int n = tid >> 7, d = tid & 127;
        float deg = degL[n];
        int j0 = d, j1 = 128 + d, j2 = 256 + d;
        float gir = pgq[0][n][j0] + pgq[1][n][j0] + pgq[2][n][j0] + pgq[3][n][j0]
                  + deg * (pgr[0][n][j0] + pgr[1][n][j0]) + pgHe[n][j0];
        float giz = pgq[0][n][j1] + pgq[1][n][j1] + pgq[2][n][j1] + pgq[3][n][j1]
                  + deg * (pgr[0][n][j1] + pgr[1][n][j1]) + pgHe[n][j1];
        float gin = pgq[0][n][j2] + pgq[1][n][j2] + pgq[2][n][j2] + pgq[3][n][j2]
                  + deg * (pgr[0][n][j2] + pgr[1][n][j2]) + pgHe[n][j2];
        float ghr = pgh[0][n][j0] + pgh[1][n][j0] + p.bhh[t * 384 + j0];
        float ghz = pgh[0][n][j1] + pgh[1][n][j1] + p.bhh[t * 384 + j1];
        float ghn = pgh[0][n][j2] + pgh[1][n][j2] + p.bhh[t * 384 + j2];
        float rr_ = 1.f / (1.f + expf(-(gir + ghr)));
        float z = 1.f / (1.f + expf(-(giz + ghz)));
        float nc = tanhf(gin + rr_ * ghn);
        float old = hv_f[n][d];
        bool upd = (hasEL != 0) && (aliveL[n] != 0);
        float nv = upd ? (1.f - z) * nc + z * old : old;
        if (t == 1 && (myv4 + n) == victimL) nv = 0.f;
        hv_f[n][d] = nv;
        float pnv = __shfl_xor(nv, 1);
        if ((tid & 1) == 0) {
          uint pk = (uint)f2bf(nv) | ((uint)f2bf(pnv) << 16);
          hv_u[n][d >> 1] = pk;
          st_devu(&nxtb[(size_t)(myv4 + n) * 64 + (d >> 1)], pk);
        }
      }

      // ---- early retirement: all 4 nodes dead forever after this round ----
      if (t == 1 && s == bexitS) {
        // nxtb rows are zero (dead). Zero our rows in curb too, then post forever.
        if (tid < 256) st_devu((uint*)&curb[(size_t)(myv4 + (tid >> 6)) * 64 + (tid & 63)], 0u);
        __syncthreads();   // drain stores before slot post
        if (tid == 0)
          __hip_atomic_store(&p.slots[blockIdx.x], 0x7FFFFFFFu, __ATOMIC_RELAXED, __HIP_MEMORY_SCOPE_AGENT);
        return;
      }

      const uint* tmp = nxtb; nxtb = (uint*)curb; curb = tmp;
    }
  }

  // ---------- Epilogue: survivor's block writes hv from its own LDS ----------
  if ((surv >> 2) == (int)blockIdx.x && tid < 128) {
    p.out[tid] = hv_f[surv & 3][tid];
  }
}

extern "C" void kernel_launch(void* const* d_in, const int* in_sizes, int n_in,
                              void* d_out, int out_size, void* d_ws, size_t ws_size,
                              hipStream_t stream) {
  (void)in_sizes; (void)n_in; (void)out_size; (void)ws_size;
  GDParams p;
  p.node_types = (const int*)d_in[0];
  p.esrc = (const int*)d_in[1];
  p.edst = (const int*)d_in[2];
  p.he   = (const float*)d_in[3];
  p.enc_W = (const float*)d_in[4];
  p.enc_b = (const float*)d_in[5];
  p.msg_W = (const float*)d_in[6];
  p.msg_b = (const float*)d_in[7];
  p.Wih = (const float*)d_in[8];
  p.Whh = (const float*)d_in[9];
  p.bih = (const float*)d_in[10];
  p.bhh = (const float*)d_in[11];

  char* w = (char*)d_ws;
  auto take = [&](size_t n) { char* r = w; w += (n + 255) & ~(size_t)255; return r; };
  p.bar   = (unsigned*)take(256);
  p.slots = (unsigned*)take(256);
  p.bufb0 = (uint*)take(8192 * 4);
  p.bufb1 = (uint*)take(8192 * 4);
  p.g     = (float*)take(16256 * 4);
  p.Wp    = (unsigned short*)take((size_t)294912 * 2);
  p.W2T   = (float*)take(12288 * 4);
  p.bm2   = (float*)take(768 * 4);
  p.HeSum = (float*)take((size_t)16256 * 16 * 4);
  p.degs  = (float*)take(16256 * 4);
  p.alive = (unsigned char*)take(16384);
  p.hasE  = (unsigned char*)take(256);
  p.victims  = (int*)take(STEPS * 4);
  p.row_ptr  = (int*)take(129 * 4);
  p.in_count = (int*)take(128 * 4);
  p.cursor   = (int*)take(128 * 4);
  p.col_src  = (int*)take(2048 * 4);
  p.col_eid  = (int*)take(2048 * 4);
  p.misc     = (int*)take(1024);
  p.out = (float*)d_out;

  (void)hipMemsetAsync(p.bar, 0, 512, stream);   // bar + slots must start at 0
  void* args[] = { (void*)&p };
  hipError_t err = hipLaunchCooperativeKernel(reinterpret_cast<void*>(gd_main),
                                              dim3(NBLK), dim3(NTHR), args, 0, stream);
  if (err != hipSuccess) {
    hipLaunchKernelGGL(gd_main, dim3(NBLK), dim3(NTHR), 0, stream, p);
  }
}

// Round 7
// 3821.991 us; speedup vs baseline: 1.1537x; 1.1537x over previous
//
#include <hip/hip_runtime.h>
#include <math.h>
#include <stdint.h>

#define STEPS 127
#define NBLK 64
#define NTHR 512
#define CAP 160

typedef unsigned int uint;

struct GDParams {
  const int* node_types; const int* esrc; const int* edst; const float* he;
  const float* enc_W; const float* enc_b; const float* msg_W; const float* msg_b;
  const float* Wih; const float* Whh; const float* bih; const float* bhh;
  unsigned* bar;          // [0]=counter [1]=generation (setup barrier)
  unsigned* slots;        // [NBLK] per-block round slots (fast barrier)
  uint* bufb0; uint* bufb1;   // hv published as bf16 pairs [128][64]
  float* g;               // 16256 gumbel values
  unsigned short* Wp;     // bf16 packed weights [mt(6)][kc(16)][j(384)][8k]
  float* W2T;             // [2][16][384] f32
  float* bm2;             // [2][384]
  float* HeSum;           // [127][128][16]
  float* degs;            // [127][128]
  unsigned char* alive;   // [127][128]
  unsigned char* hasE;    // [127]
  int* victims; int* row_ptr; int* in_count; int* cursor; int* col_src; int* col_eid;
  int* misc;              // [0]=survivor, [1+v]=death step (127 = never)
  float* out;             // 257 floats: hv[surv](128) | victim_order(128) | logps(1)
};

__device__ __forceinline__ void tfround(unsigned &x0, unsigned &x1, int r) {
  x0 += x1; x1 = (x1 << r) | (x1 >> (32 - r)); x1 ^= x0;
}
__device__ void threefry2x32(unsigned k0, unsigned k1, unsigned c0, unsigned c1,
                             unsigned &o0, unsigned &o1) {
  unsigned ks2 = k0 ^ k1 ^ 0x1BD11BDAu;
  unsigned x0 = c0 + k0, x1 = c1 + k1;
  tfround(x0,x1,13); tfround(x0,x1,15); tfround(x0,x1,26); tfround(x0,x1,6);
  x0 += k1; x1 += ks2 + 1u;
  tfround(x0,x1,17); tfround(x0,x1,29); tfround(x0,x1,16); tfround(x0,x1,24);
  x0 += ks2; x1 += k0 + 2u;
  tfround(x0,x1,13); tfround(x0,x1,15); tfround(x0,x1,26); tfround(x0,x1,6);
  x0 += k0; x1 += k1 + 3u;
  tfround(x0,x1,17); tfround(x0,x1,29); tfround(x0,x1,16); tfround(x0,x1,24);
  x0 += k1; x1 += ks2 + 4u;
  tfround(x0,x1,13); tfround(x0,x1,15); tfround(x0,x1,26); tfround(x0,x1,6);
  x0 += ks2; x1 += k0 + 5u;
  o0 = x0; o1 = x1;
}
__device__ __forceinline__ float gumbel_from_bits(unsigned b) {
  unsigned fb = (b >> 9) | 0x3F800000u;
  float f = __uint_as_float(fb) - 1.0f;
  const float tiny = 1.17549435e-38f;
  float u = fmaxf(tiny, f * (1.0f - tiny) + tiny);
  return -logf(-logf(u));
}

__device__ __forceinline__ unsigned short f2bf(float f) {
  unsigned u = __float_as_uint(f);
  unsigned r = (u + 0x7FFFu + ((u >> 16) & 1u)) >> 16;
  return (unsigned short)r;
}
__device__ __forceinline__ float bflo(uint w) { return __uint_as_float(w << 16); }
__device__ __forceinline__ float bfhi(uint w) { return __uint_as_float(w & 0xFFFF0000u); }

#if __has_builtin(__builtin_amdgcn_fdot2_f32_bf16)
typedef __bf16 bf2 __attribute__((ext_vector_type(2)));
__device__ __forceinline__ float dot2bf(uint a, uint b, float c) {
  return __builtin_amdgcn_fdot2_f32_bf16(__builtin_bit_cast(bf2, a),
                                         __builtin_bit_cast(bf2, b), c, false);
}
#else
__device__ __forceinline__ float dot2bf(uint a, uint b, float c) {
  return fmaf(bflo(a), bflo(b), fmaf(bfhi(a), bfhi(b), c));
}
#endif

// sc1 (agent-coherent) data path
__device__ __forceinline__ uint ld_devu(const uint* a) {
  return __hip_atomic_load(const_cast<uint*>(a), __ATOMIC_RELAXED, __HIP_MEMORY_SCOPE_AGENT);
}
__device__ __forceinline__ void st_devu(uint* a, uint v) {
  __hip_atomic_store(a, v, __ATOMIC_RELAXED, __HIP_MEMORY_SCOPE_AGENT);
}

// heavyweight setup barrier (acq/rel; publishes plain-written setup data)
__device__ __forceinline__ void gsync(unsigned* bar, unsigned &mygen) {
  __syncthreads();
  mygen++;
  if (threadIdx.x == 0) {
    unsigned prev = __hip_atomic_fetch_add(&bar[0], 1u, __ATOMIC_ACQ_REL, __HIP_MEMORY_SCOPE_AGENT);
    if (prev == (unsigned)(gridDim.x - 1u)) {
      __hip_atomic_store(&bar[0], 0u, __ATOMIC_RELAXED, __HIP_MEMORY_SCOPE_AGENT);
      __hip_atomic_store(&bar[1], mygen, __ATOMIC_RELEASE, __HIP_MEMORY_SCOPE_AGENT);
    } else {
      long guard = 0;
      while (__hip_atomic_load(&bar[1], __ATOMIC_ACQUIRE, __HIP_MEMORY_SCOPE_AGENT) != mygen) {
        if (++guard > (1L << 30)) break;
      }
    }
  }
  __syncthreads();
}

__global__ __launch_bounds__(NTHR, 1) void gd_main(GDParams p) {
  __shared__ float pgq[8][2][384];            // Wq partials [wave][node][j]
  __shared__ float pgr[2][2][384];            // Wr partials [khalf][node][j]
  __shared__ float pgh[2][2][384];            // Whh partials
  __shared__ float pgHe[2][384];              // He + bih + deg*bm2
  __shared__ alignas(16) uint S_u[2][64];     // S bf16-pairs
  __shared__ alignas(16) uint hv_u[2][64];    // own hv bf16-pairs
  __shared__ float hv_f[2][128];              // own hv fp32 master
  __shared__ int colL[2][CAP];
  __shared__ int cntL[2]; __shared__ int rpL[2];
  __shared__ float degL[2]; __shared__ int aliveL[2];
  __shared__ int victimL; __shared__ int hasEL;
  __shared__ unsigned relay;                  // wave0 -> waves1-3 LDS release
  __shared__ int pfs[128];

  const int tid = threadIdx.x;
  const int gtid = blockIdx.x * NTHR + tid;
  const int GSZ = NBLK * NTHR;
  unsigned mygen = 0;

  // ---------- Stage A ----------
  if (blockIdx.x == 0) {
    // jax_threefry_partitionable (default since 0.4.36): ctr=(0,i), bits=o0^o1
    for (int i = tid; i < 16256; i += NTHR) {
      unsigned o0, o1; threefry2x32(0u, 42u, 0u, (unsigned)i, o0, o1);
      p.g[i] = gumbel_from_bits(o0 ^ o1);
    }
    __syncthreads();
    if (tid < 64) {
      int lane = tid;
      bool a0 = true, a1 = true;
      float lsum = 0.f;
      p.misc[1 + lane] = 127; p.misc[1 + 64 + lane] = 127;
      for (int s = 0; s < STEPS; ++s) {
        p.alive[s * 128 + lane] = a0 ? 1 : 0;
        p.alive[s * 128 + 64 + lane] = a1 ? 1 : 0;
        float c = logf(1.0f / (float)(128 - s));
        float g0 = a0 ? (c + p.g[s * 128 + lane]) : -INFINITY;
        float g1 = a1 ? (c + p.g[s * 128 + 64 + lane]) : -INFINITY;
        float bv; int bi;
        if (g0 >= g1) { bv = g0; bi = lane; } else { bv = g1; bi = lane + 64; }
        for (int off = 32; off > 0; off >>= 1) {
          float ov = __shfl_down(bv, off);
          int   oi = __shfl_down(bi, off);
          if (ov > bv || (ov == bv && oi < bi)) { bv = ov; bi = oi; }
        }
        int victim = __shfl(bi, 0);
        if (victim == lane) { a0 = false; p.misc[1 + lane] = s; }
        if (victim == lane + 64) { a1 = false; p.misc[1 + 64 + lane] = s; }
        lsum += c;
        if (lane == 0) {
          p.victims[s] = victim;
          p.out[128 + 127 - s] = (float)victim;
        }
      }
      unsigned long long m0 = __ballot(a0), m1 = __ballot(a1);
      int surv = m0 ? (__ffsll(m0) - 1) : (64 + __ffsll(m1) - 1);
      if (lane == 0) { p.misc[0] = surv; p.out[128] = (float)surv; p.out[256] = lsum; }
    }
  } else {
    const int g63 = (blockIdx.x - 1) * NTHR + tid;
    const int GSZ63 = (NBLK - 1) * NTHR;
    for (int i = g63; i < 128; i += GSZ63) { p.in_count[i] = 0; p.cursor[i] = 0; }
    // hv0 published as bf16 pairs
    for (int i = g63; i < 8192; i += GSZ63) {
      int v = i >> 6, up = i & 63;
      int ty = p.node_types[v];
      float h0 = p.enc_W[(2 * up) * 32 + ty] + p.enc_b[2 * up];
      float h1 = p.enc_W[(2 * up + 1) * 32 + ty] + p.enc_b[2 * up + 1];
      p.bufb0[i] = (uint)f2bf(h0) | ((uint)f2bf(h1) << 16);
    }
    // folded Wq = Wih@Wa (mat 0), Wr = Wih@Wb (mat 1) -> bf16 packed layout
    for (int o = g63; o < 196608; o += GSZ63) {
      int mat = o / 98304; int r = o % 98304; int t = r / 49152; int rr = r % 49152;
      int k = rr / 384, j = rr % 384;
      const float* wih = p.Wih + (size_t)(t * 384 + j) * 128;
      const float* mw  = p.msg_W + (size_t)t * 128 * 272 + (mat * 128 + k);
      float acc = 0.f;
      for (int m = 0; m < 128; ++m) acc += wih[m] * mw[(size_t)m * 272];
      int mt = mat * 2 + t;
      p.Wp[(size_t)((mt * 16 + (k >> 3)) * 384 + j) * 8 + (k & 7)] = f2bf(acc);
    }
    // Whh -> bf16 packed (mt = 4+t)
    for (int o = g63; o < 98304; o += GSZ63) {
      int t = o / 49152; int rr = o % 49152; int k = rr / 384, j = rr % 384;
      float acc = p.Whh[(size_t)(t * 384 + j) * 128 + k];
      int mt = 4 + t;
      p.Wp[(size_t)((mt * 16 + (k >> 3)) * 384 + j) * 8 + (k & 7)] = f2bf(acc);
    }
    // W2T = (Wih@We)^T f32 [t][16][384]
    for (int o = g63; o < 12288; o += GSZ63) {
      int t = o / 6144; int rr = o % 6144; int k = rr / 384, j = rr % 384;
      const float* wih = p.Wih + (size_t)(t * 384 + j) * 128;
      const float* mw  = p.msg_W + (size_t)t * 128 * 272 + (256 + k);
      float acc = 0.f;
      for (int m = 0; m < 128; ++m) acc += wih[m] * mw[(size_t)m * 272];
      p.W2T[(size_t)(t * 16 + k) * 384 + j] = acc;
    }
    // bm2 = Wih @ msg_b
    for (int o = g63; o < 768; o += GSZ63) {
      int t = o / 384, j = o % 384;
      const float* wih = p.Wih + (size_t)(t * 384 + j) * 128;
      const float* mb = p.msg_b + t * 128;
      float acc = 0.f;
      for (int m = 0; m < 128; ++m) acc += wih[m] * mb[m];
      p.bm2[o] = acc;
    }
  }
  gsync(p.bar, mygen);

  // ---------- Stage B: in-degree histogram ----------
  if (blockIdx.x != 0) {
    for (int e = (blockIdx.x - 1) * NTHR + tid; e < 2048; e += (NBLK - 1) * NTHR)
      atomicAdd(&p.in_count[p.edst[e]], 1);
  }
  gsync(p.bar, mygen);

  // ---------- Stage C: prefix sum (block 0) ----------
  if (blockIdx.x == 0) {
    if (tid < 128) pfs[tid] = p.in_count[tid];
    __syncthreads();
    for (int off = 1; off < 128; off <<= 1) {
      int add = 0;
      if (tid < 128 && tid >= off) add = pfs[tid - off];
      __syncthreads();
      if (tid < 128) pfs[tid] += add;
      __syncthreads();
    }
    if (tid == 0) p.row_ptr[0] = 0;
    if (tid < 128) p.row_ptr[tid + 1] = pfs[tid];
  }
  gsync(p.bar, mygen);

  // ---------- Stage D: CSR scatter ----------
  for (int e = gtid; e < 2048; e += GSZ) {
    int dd = p.edst[e];
    int pos = atomicAdd(&p.cursor[dd], 1);
    int q = p.row_ptr[dd] + pos;
    p.col_src[q] = p.esrc[e];
    p.col_eid[q] = e;
  }
  gsync(p.bar, mygen);

  // ---------- Stage E: per-step deg / HeSum ----------
  for (int i = gtid; i < 16256; i += GSZ) {
    int s = i >> 7, v = i & 127;
    int rp0 = p.row_ptr[v], rp1 = p.row_ptr[v + 1];
    const unsigned char* al = p.alive + s * 128;
    float deg = 0.f; float hacc[16];
    #pragma unroll
    for (int k = 0; k < 16; ++k) hacc[k] = 0.f;
    for (int q = rp0; q < rp1; ++q) {
      int u = p.col_src[q];
      if (al[u]) {
        deg += 1.f;
        const float* hr = p.he + (size_t)p.col_eid[q] * 16;
        #pragma unroll
        for (int k = 0; k < 16; ++k) hacc[k] += hr[k];
      }
    }
    p.degs[i] = deg;
    float* ho = p.HeSum + (size_t)i * 16;
    #pragma unroll
    for (int k = 0; k < 16; ++k) ho[k] = hacc[k];
  }
  gsync(p.bar, mygen);

  // ---------- Stage F: has_edges + per-block CSR preload ----------
  for (int s = gtid; s < STEPS; s += GSZ) {
    float acc = 0.f;
    for (int v = 0; v < 128; ++v)
      acc += p.alive[s * 128 + v] ? p.degs[s * 128 + v] : 0.f;
    p.hasE[s] = (acc > 0.f) ? 1 : 0;
  }
  for (int vv = 0; vv < 2; ++vv) {
    int v = blockIdx.x * 2 + vv;
    int rp0 = p.row_ptr[v], rp1 = p.row_ptr[v + 1];
    if (tid == 0) { cntL[vv] = rp1 - rp0; rpL[vv] = rp0; }
    int n = rp1 - rp0; if (n > CAP) n = CAP;
    for (int q = tid; q < n; q += NTHR) colL[vv][q] = p.col_src[rp0 + q];
  }
  if (tid == 0) relay = 0;
  gsync(p.bar, mygen);   // publishes all setup data

  // ---------- Main loop ----------
  const uint* curb = p.bufb0; uint* nxtb = p.bufb1;
  const int wave = tid >> 6, lane6 = tid & 63;
  const int myv2 = blockIdx.x * 2;
  const uint4* Wp4 = (const uint4*)p.Wp;

  const int surv = p.misc[0];
  const int bexitS = max(p.misc[1 + myv2], p.misc[2 + myv2]);  // 127 if survivor here

  // init hv mirrors
  if (tid < 256) {
    int n = tid >> 7, d = tid & 127;
    int ty = p.node_types[myv2 + n];
    float h0 = p.enc_W[d * 32 + ty] + p.enc_b[d];
    hv_f[n][d] = h0;
    float ph = __shfl_xor(h0, 1);
    if ((tid & 1) == 0) hv_u[n][d >> 1] = (uint)f2bf(h0) | ((uint)f2bf(ph) << 16);
  }
  __syncthreads();

  unsigned r = 0;
  for (int s = 0; s < STEPS; ++s) {
    for (int t = 0; t < 2; ++t) {
      r++;
      // ---- post: drain hv stores, fire slot ----
      __syncthreads();
      if (tid == 0)
        __hip_atomic_store(&p.slots[blockIdx.x], r, __ATOMIC_RELAXED, __HIP_MEMORY_SCOPE_AGENT);

      if (wave < 4) {
        // ===== barrier + gather group (NO pre-barrier work) =====
        if (wave == 0) {
          long guard = 0;
          for (;;) {
            unsigned v = __hip_atomic_load(&p.slots[lane6], __ATOMIC_RELAXED, __HIP_MEMORY_SCOPE_AGENT);
            if (__all(v >= r)) break;
            __builtin_amdgcn_s_sleep(1);
            if (++guard > (1L << 20)) break;
          }
          if (lane6 == 0)
            __hip_atomic_store(&relay, r, __ATOMIC_RELEASE, __HIP_MEMORY_SCOPE_WORKGROUP);
        } else {
          long guard = 0;
          while (__hip_atomic_load(&relay, __ATOMIC_ACQUIRE, __HIP_MEMORY_SCOPE_WORKGROUP) < r) {
            if (++guard > (1L << 24)) break;
          }
        }
        // gather: wave -> (node, dim-half); lane -> (i, edge-parity)
        {
          const int n = wave >> 1, half = wave & 1;
          const int i = lane6 >> 1, e = lane6 & 1;
          const int u = half * 32 + i;
          int cnt = cntL[n];
          int cmin = cnt < CAP ? cnt : CAP;
          float aL = 0.f, aH = 0.f;
          int q = e;
          for (; q + 14 < cmin; q += 16) {
            int c0 = colL[n][q],      c1 = colL[n][q + 2],  c2 = colL[n][q + 4],  c3 = colL[n][q + 6];
            int c4 = colL[n][q + 8],  c5 = colL[n][q + 10], c6 = colL[n][q + 12], c7 = colL[n][q + 14];
            uint w0 = ld_devu(&curb[(size_t)c0 * 64 + u]);
            uint w1 = ld_devu(&curb[(size_t)c1 * 64 + u]);
            uint w2 = ld_devu(&curb[(size_t)c2 * 64 + u]);
            uint w3 = ld_devu(&curb[(size_t)c3 * 64 + u]);
            uint w4 = ld_devu(&curb[(size_t)c4 * 64 + u]);
            uint w5 = ld_devu(&curb[(size_t)c5 * 64 + u]);
            uint w6 = ld_devu(&curb[(size_t)c6 * 64 + u]);
            uint w7 = ld_devu(&curb[(size_t)c7 * 64 + u]);
            aL += ((bflo(w0) + bflo(w1)) + (bflo(w2) + bflo(w3)))
                + ((bflo(w4) + bflo(w5)) + (bflo(w6) + bflo(w7)));
            aH += ((bfhi(w0) + bfhi(w1)) + (bfhi(w2) + bfhi(w3)))
                + ((bfhi(w4) + bfhi(w5)) + (bfhi(w6) + bfhi(w7)));
          }
          for (; q < cnt; q += 2) {
            int c = (q < CAP) ? colL[n][q] : p.col_src[rpL[n] + q];
            uint w = ld_devu(&curb[(size_t)c * 64 + u]);
            aL += bflo(w); aH += bfhi(w);
          }
          aL += __shfl_xor(aL, 1);
          aH += __shfl_xor(aH, 1);
          if (e == 0) S_u[n][u] = (uint)f2bf(aL) | ((uint)f2bf(aH) << 16);
        }
      } else {
        // ===== local group: step scalars + Wr/Whh GEMVs + He/bias =====
        if (tid == 256) { victimL = p.victims[s]; hasEL = p.hasE[s]; }
        if (tid >= 258 && tid < 260) {
          int n = tid - 258;
          degL[n] = p.degs[s * 128 + myv2 + n];
          aliveL[n] = p.alive[s * 128 + myv2 + n];
        }
        {
          const int mm = (wave >= 6) ? 1 : 0;   // 0=Wr, 1=Whh
          const int H = wave & 1;
          const uint4* WM = Wp4 + (size_t)((mm ? 4 : 2) + t) * 6144;
          const uint4* A0 = (const uint4*)&hv_u[0][0];
          const uint4* A1 = (const uint4*)&hv_u[1][0];
          float acc[6][2] = {};
          #pragma unroll
          for (int kc = 0; kc < 8; ++kc) {
            int kcg = H * 8 + kc;
            uint4 a0 = A0[kcg], a1 = A1[kcg];
            #pragma unroll
            for (int jj = 0; jj < 6; ++jj) {
              uint4 wv = WM[(size_t)kcg * 384 + lane6 + 64 * jj];
              acc[jj][0] = dot2bf(a0.x, wv.x, acc[jj][0]);
              acc[jj][0] = dot2bf(a0.y, wv.y, acc[jj][0]);
              acc[jj][0] = dot2bf(a0.z, wv.z, acc[jj][0]);
              acc[jj][0] = dot2bf(a0.w, wv.w, acc[jj][0]);
              acc[jj][1] = dot2bf(a1.x, wv.x, acc[jj][1]);
              acc[jj][1] = dot2bf(a1.y, wv.y, acc[jj][1]);
              acc[jj][1] = dot2bf(a1.z, wv.z, acc[jj][1]);
              acc[jj][1] = dot2bf(a1.w, wv.w, acc[jj][1]);
            }
          }
          float (*dst)[2][384] = mm ? pgh : pgr;
          #pragma unroll
          for (int jj = 0; jj < 6; ++jj) {
            dst[H][0][lane6 + 64 * jj] = acc[jj][0];
            dst[H][1][lane6 + 64 * jj] = acc[jj][1];
          }
        }
        // He + biases: 768 slots over these 256 threads
        {
          int base = tid - 256;
          #pragma unroll
          for (int ii = 0; ii < 3; ++ii) {
            int idx = base + 256 * ii;
            int n2 = (idx >= 384) ? 1 : 0;
            int j = idx - n2 * 384;
            int v = myv2 + n2;
            float dg = p.degs[s * 128 + v];
            float a = p.bih[t * 384 + j] + dg * p.bm2[t * 384 + j];
            const float* hs = p.HeSum + ((size_t)s * 128 + v) * 16;
            #pragma unroll
            for (int k2 = 0; k2 < 16; ++k2)
              a += hs[k2] * p.W2T[(size_t)(t * 16 + k2) * 384 + j];
            pgHe[n2][j] = a;
          }
        }
      }
      __syncthreads();   // join: S ready, pgr/pgh/pgHe ready

      // ---- Wq . S on all 8 waves (2 kc each) ----
      {
        const uint4* WQ = Wp4 + (size_t)t * 6144;
        const uint4* A0 = (const uint4*)&S_u[0][0];
        const uint4* A1 = (const uint4*)&S_u[1][0];
        float acc[6][2] = {};
        #pragma unroll
        for (int kc = 0; kc < 2; ++kc) {
          int kcg = wave * 2 + kc;
          uint4 a0 = A0[kcg], a1 = A1[kcg];
          #pragma unroll
          for (int jj = 0; jj < 6; ++jj) {
            uint4 wv = WQ[(size_t)kcg * 384 + lane6 + 64 * jj];
            acc[jj][0] = dot2bf(a0.x, wv.x, acc[jj][0]);
            acc[jj][0] = dot2bf(a0.y, wv.y, acc[jj][0]);
            acc[jj][0] = dot2bf(a0.z, wv.z, acc[jj][0]);
            acc[jj][0] = dot2bf(a0.w, wv.w, acc[jj][0]);
            acc[jj][1] = dot2bf(a1.x, wv.x, acc[jj][1]);
            acc[jj][1] = dot2bf(a1.y, wv.y, acc[jj][1]);
            acc[jj][1] = dot2bf(a1.z, wv.z, acc[jj][1]);
            acc[jj][1] = dot2bf(a1.w, wv.w, acc[jj][1]);
          }
        }
        #pragma unroll
        for (int jj = 0; jj < 6; ++jj) {
          pgq[wave][0][lane6 + 64 * jj] = acc[jj][0];
          pgq[wave][1][lane6 + 64 * jj] = acc[jj][1];
        }
      }
      __syncthreads();

      // ---- gates + hv update + publish ----
      if (tid < 256) {
        int n = tid >> 7, d = tid & 127;
        float deg = degL[n];
        int j0 = d, j1 = 128 + d, j2 = 256 + d;
        float q0 = 0.f, q1 = 0.f, q2 = 0.f;
        #pragma unroll
        for (int w8 = 0; w8 < 8; ++w8) {
          q0 += pgq[w8][n][j0]; q1 += pgq[w8][n][j1]; q2 += pgq[w8][n][j2];
        }
        float gir = q0 + deg * (pgr[0][n][j0] + pgr[1][n][j0]) + pgHe[n][j0];
        float giz = q1 + deg * (pgr[0][n][j1] + pgr[1][n][j1]) + pgHe[n][j1];
        float gin = q2 + deg * (pgr[0][n][j2] + pgr[1][n][j2]) + pgHe[n][j2];
        float ghr = pgh[0][n][j0] + pgh[1][n][j0] + p.bhh[t * 384 + j0];
        float ghz = pgh[0][n][j1] + pgh[1][n][j1] + p.bhh[t * 384 + j1];
        float ghn = pgh[0][n][j2] + pgh[1][n][j2] + p.bhh[t * 384 + j2];
        float rr_ = 1.f / (1.f + expf(-(gir + ghr)));
        float z = 1.f / (1.f + expf(-(giz + ghz)));
        float nc = tanhf(gin + rr_ * ghn);
        float old = hv_f[n][d];
        bool upd = (hasEL != 0) && (aliveL[n] != 0);
        float nv = upd ? (1.f - z) * nc + z * old : old;
        if (t == 1 && (myv2 + n) == victimL) nv = 0.f;
        hv_f[n][d] = nv;
        float pnv = __shfl_xor(nv, 1);
        if ((tid & 1) == 0) {
          uint pk = (uint)f2bf(nv) | ((uint)f2bf(pnv) << 16);
          hv_u[n][d >> 1] = pk;
          st_devu(&nxtb[(size_t)(myv2 + n) * 64 + (d >> 1)], pk);
        }
      }

      // ---- early retirement: both nodes dead forever after this round ----
      if (t == 1 && s == bexitS) {
        if (tid < 128) st_devu((uint*)&curb[(size_t)myv2 * 64 + tid], 0u);
        __syncthreads();   // drain stores before slot post
        if (tid == 0)
          __hip_atomic_store(&p.slots[blockIdx.x], 0x7FFFFFFFu, __ATOMIC_RELAXED, __HIP_MEMORY_SCOPE_AGENT);
        return;
      }

      const uint* tmp = nxtb; nxtb = (uint*)curb; curb = tmp;
    }
  }

  // ---------- Epilogue: survivor's block writes hv from its own LDS ----------
  if ((surv >> 1) == (int)blockIdx.x && tid < 128) {
    p.out[tid] = hv_f[surv & 1][tid];
  }
}

extern "C" void kernel_launch(void* const* d_in, const int* in_sizes, int n_in,
                              void* d_out, int out_size, void* d_ws, size_t ws_size,
                              hipStream_t stream) {
  (void)in_sizes; (void)n_in; (void)out_size; (void)ws_size;
  GDParams p;
  p.node_types = (const int*)d_in[0];
  p.esrc = (const int*)d_in[1];
  p.edst = (const int*)d_in[2];
  p.he   = (const float*)d_in[3];
  p.enc_W = (const float*)d_in[4];
  p.enc_b = (const float*)d_in[5];
  p.msg_W = (const float*)d_in[6];
  p.msg_b = (const float*)d_in[7];
  p.Wih = (const float*)d_in[8];
  p.Whh = (const float*)d_in[9];
  p.bih = (const float*)d_in[10];
  p.bhh = (const float*)d_in[11];

  char* w = (char*)d_ws;
  auto take = [&](size_t n) { char* r = w; w += (n + 255) & ~(size_t)255; return r; };
  p.bar   = (unsigned*)take(256);
  p.slots = (unsigned*)take(256);
  p.bufb0 = (uint*)take(8192 * 4);
  p.bufb1 = (uint*)take(8192 * 4);
  p.g     = (float*)take(16256 * 4);
  p.Wp    = (unsigned short*)take((size_t)294912 * 2);
  p.W2T   = (float*)take(12288 * 4);
  p.bm2   = (float*)take(768 * 4);
  p.HeSum = (float*)take((size_t)16256 * 16 * 4);
  p.degs  = (float*)take(16256 * 4);
  p.alive = (unsigned char*)take(16384);
  p.hasE  = (unsigned char*)take(256);
  p.victims  = (int*)take(STEPS * 4);
  p.row_ptr  = (int*)take(129 * 4);
  p.in_count = (int*)take(128 * 4);
  p.cursor   = (int*)take(128 * 4);
  p.col_src  = (int*)take(2048 * 4);
  p.col_eid  = (int*)take(2048 * 4);
  p.misc     = (int*)take(1024);
  p.out = (float*)d_out;

  (void)hipMemsetAsync(p.bar, 0, 512, stream);   // bar + slots must start at 0
  void* args[] = { (void*)&p };
  hipError_t err = hipLaunchCooperativeKernel(reinterpret_cast<void*>(gd_main),
                                              dim3(NBLK), dim3(NTHR), args, 0, stream);
  if (err != hipSuccess) {
    hipLaunchKernelGGL(gd_main, dim3(NBLK), dim3(NTHR), 0, stream, p);
  }
}